// Round 2
// baseline (91.994 us; speedup 1.0000x reference)
//
#include <hip/hip_runtime.h>
#include <math.h>

#define NPTS 262144
#define B_KB 4.71238898038469f      /* 1.5*pi */
#define B_KB2 22.2066099025f        /* B_KB^2 */
#define PI_F 3.14159265358979f
#define TWO_PI_OVER_N 0.01227184630309f /* 2*pi/512 */

__device__ __forceinline__ float i0f_dev(float x) {
    float ax = fabsf(x);
    if (ax < 3.75f) {
        float t = ax / 3.75f; t *= t;
        return 1.0f + t*(3.5156229f + t*(3.0899424f + t*(1.2067492f +
               t*(0.2659732f + t*(0.0360768f + t*0.0045813f)))));
    } else {
        float t = 3.75f / ax;
        float p = 0.39894228f + t*(0.01328592f + t*(0.00225319f + t*(-0.00157565f +
                  t*(0.00916281f + t*(-0.02057706f + t*(0.02635537f +
                  t*(-0.01647633f + t*0.00392377f)))))));
        return expf(ax) * p / sqrtf(ax);
    }
}

// Build g_hat in natural (already-fftshifted) DFT order, with (-1)^(i1+i2)
// folded in so the FFT output needs no ifftshift.
__global__ void build_ghat(const float* __restrict__ fr,
                           const float* __restrict__ fi,
                           float2* __restrict__ g) {
    int idx = blockIdx.x * 256 + threadIdx.x;   // 0 .. 512*512-1
    int i1 = idx >> 9;
    int i2 = idx & 511;
    float2 val = make_float2(0.0f, 0.0f);
    int k1 = 0, k2 = 0;
    bool ok = true;
    if (i1 < 128) k1 = i1; else if (i1 >= 384) k1 = i1 - 512; else ok = false;
    if (ok) { if (i2 < 128) k2 = i2; else if (i2 >= 384) k2 = i2 - 512; else ok = false; }
    if (ok) {
        float a1 = TWO_PI_OVER_N * (float)k1;
        float a2 = TWO_PI_OVER_N * (float)k2;
        float ph1 = i0f_dev(4.0f * sqrtf(B_KB2 - a1*a1));
        float ph2 = i0f_dev(4.0f * sqrtf(B_KB2 - a2*a2));
        float inv = 1.0f / (ph1 * ph2);
        if ((i1 + i2) & 1) inv = -inv;
        int fidx = (k1 + 128) * 256 + (k2 + 128);
        val.x = fr[fidx] * inv;
        val.y = fi[fidx] * inv;
    }
    g[idx] = val;
}

// In-place 512-point radix-2 DIT FFT over lines of the 512x512 grid.
// Line l: elements at l*base_mult + j*stride, j in [0,512).
__global__ void fft_lines(float2* __restrict__ g, int base_mult, int stride) {
    __shared__ float2 buf[512];
    int line = blockIdx.x;
    int tid = threadIdx.x;      // 256 threads
    long base = (long)line * base_mult;
    for (int j = tid; j < 512; j += 256) {
        int rj = (int)(__brev((unsigned)j) >> 23);   // 9-bit reversal
        buf[rj] = g[base + (long)j * stride];
    }
    __syncthreads();
    #pragma unroll
    for (int s = 1; s <= 9; ++s) {
        int half = 1 << (s - 1);
        int pos = tid & (half - 1);
        int i1 = ((tid >> (s - 1)) << s) | pos;
        float ang = -PI_F * (float)pos / (float)half;
        float sw, cw;
        sincosf(ang, &sw, &cw);
        float2 u = buf[i1];
        float2 v = buf[i1 + half];
        float wr = cw * v.x - sw * v.y;
        float wi = cw * v.y + sw * v.x;
        buf[i1]        = make_float2(u.x + wr, u.y + wi);
        buf[i1 + half] = make_float2(u.x - wr, u.y - wi);
        __syncthreads();
    }
    for (int j = tid; j < 512; j += 256) {
        g[base + (long)j * stride] = buf[j];
    }
}

// Per nonequispaced point: separable 8x8 Kaiser-Bessel window gather.
// writeComplex=1 -> interleaved float2 per point; 0 -> real part only.
__global__ void gather_pts(const float2* __restrict__ x,
                           const float2* __restrict__ g,
                           float* __restrict__ out, int writeComplex) {
    int m = blockIdx.x * 256 + threadIdx.x;
    if (m >= NPTS) return;
    float2 xv = x[m];
    float v1 = xv.x * 512.0f;
    float v2 = xv.y * 512.0f;
    float c1 = ceilf(v1), c2 = ceilf(v2);
    int b1 = (int)c1 - 4, b2 = (int)c2 - 4;
    float f1 = c1 - v1, f2 = c2 - v2;

    float phi1[8], phi2[8];
    int id1[8], id2[8];
    #pragma unroll
    for (int w = 0; w < 8; ++w) {
        float t = 4.0f - (float)w - f1;
        float s = 16.0f - t * t;
        float p = 0.0f;
        if (s > 0.0f) { float a = sqrtf(s); p = sinhf(B_KB * a) / (a * PI_F); }
        phi1[w] = p;
        id1[w] = ((b1 + w + 768) & 511) << 9;

        t = 4.0f - (float)w - f2;
        s = 16.0f - t * t;
        p = 0.0f;
        if (s > 0.0f) { float a = sqrtf(s); p = sinhf(B_KB * a) / (a * PI_F); }
        phi2[w] = p;
        id2[w] = (b2 + w + 768) & 511;
    }

    float accx = 0.0f, accy = 0.0f;
    #pragma unroll
    for (int w1 = 0; w1 < 8; ++w1) {
        float p1 = phi1[w1];
        int row = id1[w1];
        #pragma unroll
        for (int w2 = 0; w2 < 8; ++w2) {
            float2 gv = g[row + id2[w2]];
            float wt = p1 * phi2[w2];
            accx += gv.x * wt;
            accy += gv.y * wt;
        }
    }
    if (writeComplex) {
        ((float2*)out)[m] = make_float2(accx, accy);
    } else {
        out[m] = accx;   // harness keeps only the real part of the complex ref
    }
}

extern "C" void kernel_launch(void* const* d_in, const int* in_sizes, int n_in,
                              void* d_out, int out_size, void* d_ws, size_t ws_size,
                              hipStream_t stream) {
    const float* x  = (const float*)d_in[0];
    const float* fr = (const float*)d_in[1];
    const float* fi = (const float*)d_in[2];
    float2* g = (float2*)d_ws;            // 512*512*8B = 2 MiB scratch
    int writeComplex = (out_size >= 2 * NPTS) ? 1 : 0;

    build_ghat<<<1024, 256, 0, stream>>>(fr, fi, g);
    fft_lines<<<512, 256, 0, stream>>>(g, 512, 1);   // row FFTs
    fft_lines<<<512, 256, 0, stream>>>(g, 1, 512);   // column FFTs
    gather_pts<<<1024, 256, 0, stream>>>((const float2*)x, g,
                                         (float*)d_out, writeComplex);
}

// Round 3
// 53.126 us; speedup vs baseline: 1.7316x; 1.7316x over previous
//
#include <hip/hip_runtime.h>
#include <math.h>

#define NPTS 262144
#define B_KB 4.71238898038469f      /* 1.5*pi */
#define B_KB2 22.2066099025f        /* B_KB^2 */
#define PI_F 3.14159265358979f
#define TWO_PI_OVER_N 0.01227184630309f /* 2*pi/512 */
#define NCOL 520                    /* padded row stride: 512 + 8 dup cols */

__device__ __forceinline__ float i0f_dev(float x) {
    float ax = fabsf(x);
    if (ax < 3.75f) {
        float t = ax / 3.75f; t *= t;
        return 1.0f + t*(3.5156229f + t*(3.0899424f + t*(1.2067492f +
               t*(0.2659732f + t*(0.0360768f + t*0.0045813f)))));
    } else {
        float t = 3.75f / ax;
        float p = 0.39894228f + t*(0.01328592f + t*(0.00225319f + t*(-0.00157565f +
                  t*(0.00916281f + t*(-0.02057706f + t*(0.02635537f +
                  t*(-0.01647633f + t*0.00392377f)))))));
        return expf(ax) * p / sqrtf(ax);
    }
}

// Build g_hat in natural (already-fftshifted) DFT order, with (-1)^(i1+i2)
// folded in so the FFT output needs no ifftshift. Row stride ldg.
__global__ void build_ghat(const float* __restrict__ fr,
                           const float* __restrict__ fi,
                           float2* __restrict__ g, int ldg) {
    int idx = blockIdx.x * 256 + threadIdx.x;   // 0 .. 512*512-1
    int i1 = idx >> 9;
    int i2 = idx & 511;
    float2 val = make_float2(0.0f, 0.0f);
    int k1 = 0, k2 = 0;
    bool ok = true;
    if (i1 < 128) k1 = i1; else if (i1 >= 384) k1 = i1 - 512; else ok = false;
    if (ok) { if (i2 < 128) k2 = i2; else if (i2 >= 384) k2 = i2 - 512; else ok = false; }
    if (ok) {
        float a1 = TWO_PI_OVER_N * (float)k1;
        float a2 = TWO_PI_OVER_N * (float)k2;
        float ph1 = i0f_dev(4.0f * sqrtf(B_KB2 - a1*a1));
        float ph2 = i0f_dev(4.0f * sqrtf(B_KB2 - a2*a2));
        float inv = 1.0f / (ph1 * ph2);
        if ((i1 + i2) & 1) inv = -inv;
        int fidx = (k1 + 128) * 256 + (k2 + 128);
        val.x = fr[fidx] * inv;
        val.y = fi[fidx] * inv;
    }
    g[i1 * ldg + i2] = val;
}

// In-place 512-point radix-2 DIT FFT over lines. Line l: elements at
// l*line_stride + j*elem_stride. If ndup>0 (rows pass, elem_stride==1),
// duplicate the first ndup elements at offset 512.. for column padding.
__global__ void fft_lines(float2* __restrict__ g, int line_stride,
                          int elem_stride, int ndup) {
    __shared__ float2 buf[512];
    int line = blockIdx.x;
    int tid = threadIdx.x;      // 256 threads
    long base = (long)line * line_stride;
    for (int j = tid; j < 512; j += 256) {
        int rj = (int)(__brev((unsigned)j) >> 23);   // 9-bit reversal
        buf[rj] = g[base + (long)j * elem_stride];
    }
    __syncthreads();
    #pragma unroll
    for (int s = 1; s <= 9; ++s) {
        int half = 1 << (s - 1);
        int pos = tid & (half - 1);
        int i1 = ((tid >> (s - 1)) << s) | pos;
        float ang = -PI_F * (float)pos / (float)half;
        float sw, cw;
        sincosf(ang, &sw, &cw);
        float2 u = buf[i1];
        float2 v = buf[i1 + half];
        float wr = cw * v.x - sw * v.y;
        float wi = cw * v.y + sw * v.x;
        buf[i1]        = make_float2(u.x + wr, u.y + wi);
        buf[i1 + half] = make_float2(u.x - wr, u.y - wi);
        __syncthreads();
    }
    for (int j = tid; j < 512; j += 256) {
        g[base + (long)j * elem_stride] = buf[j];
    }
    for (int j = tid; j < ndup; j += 256) {
        g[base + 512 + j] = buf[j];     // elem_stride==1 rows only
    }
}

// Padded-gather: each window row is 8 contiguous float2 (cols cb..cb+7 < 520),
// loaded as 4x float4. No wrap path.
template<int COMPLEX>
__global__ __launch_bounds__(256, 4)
void gather_pad(const float2* __restrict__ x,
                const float2* __restrict__ g,
                float* __restrict__ out) {
    int m = blockIdx.x * 256 + threadIdx.x;
    float2 xv = x[m];
    float v1 = xv.x * 512.0f;
    float v2 = xv.y * 512.0f;
    float c1 = ceilf(v1), c2 = ceilf(v2);
    int b1 = (int)c1 - 4, b2 = (int)c2 - 4;
    float f1 = c1 - v1, f2 = c2 - v2;

    float phi1[8], phi2[8];
    int rowb[8];
    #pragma unroll
    for (int w = 0; w < 8; ++w) {
        float t = 4.0f - (float)w - f1;
        float s = 16.0f - t * t;
        float p = 0.0f;
        if (s > 0.0f) { float a = sqrtf(s); p = sinhf(B_KB * a) / (a * PI_F); }
        phi1[w] = p;
        rowb[w] = ((b1 + w + 768) & 511) * NCOL;

        t = 4.0f - (float)w - f2;
        s = 16.0f - t * t;
        p = 0.0f;
        if (s > 0.0f) { float a = sqrtf(s); p = sinhf(B_KB * a) / (a * PI_F); }
        phi2[w] = p;
    }
    int cb = (b2 + 768) & 511;

    float accx = 0.0f, accy = 0.0f;
    #pragma unroll
    for (int w1 = 0; w1 < 8; ++w1) {
        const float4* p = reinterpret_cast<const float4*>(g + rowb[w1] + cb);
        float4 va = p[0], vb = p[1], vc = p[2], vd = p[3];
        float p1 = phi1[w1];
        accx += p1 * (phi2[0]*va.x + phi2[1]*va.z + phi2[2]*vb.x + phi2[3]*vb.z +
                      phi2[4]*vc.x + phi2[5]*vc.z + phi2[6]*vd.x + phi2[7]*vd.z);
        if (COMPLEX)
            accy += p1 * (phi2[0]*va.y + phi2[1]*va.w + phi2[2]*vb.y + phi2[3]*vb.w +
                          phi2[4]*vc.y + phi2[5]*vc.w + phi2[6]*vd.y + phi2[7]*vd.w);
    }
    if (COMPLEX) ((float2*)out)[m] = make_float2(accx, accy);
    else out[m] = accx;   // harness keeps only the real part of the complex ref
}

// Fallback (compact 512x512, per-element column mod) — used if ws too small.
template<int COMPLEX>
__global__ void gather_mod(const float2* __restrict__ x,
                           const float2* __restrict__ g,
                           float* __restrict__ out) {
    int m = blockIdx.x * 256 + threadIdx.x;
    float2 xv = x[m];
    float v1 = xv.x * 512.0f;
    float v2 = xv.y * 512.0f;
    float c1 = ceilf(v1), c2 = ceilf(v2);
    int b1 = (int)c1 - 4, b2 = (int)c2 - 4;
    float f1 = c1 - v1, f2 = c2 - v2;

    float phi1[8], phi2[8];
    int id1[8], id2[8];
    #pragma unroll
    for (int w = 0; w < 8; ++w) {
        float t = 4.0f - (float)w - f1;
        float s = 16.0f - t * t;
        float p = 0.0f;
        if (s > 0.0f) { float a = sqrtf(s); p = sinhf(B_KB * a) / (a * PI_F); }
        phi1[w] = p;
        id1[w] = ((b1 + w + 768) & 511) << 9;

        t = 4.0f - (float)w - f2;
        s = 16.0f - t * t;
        p = 0.0f;
        if (s > 0.0f) { float a = sqrtf(s); p = sinhf(B_KB * a) / (a * PI_F); }
        phi2[w] = p;
        id2[w] = (b2 + w + 768) & 511;
    }

    float accx = 0.0f, accy = 0.0f;
    #pragma unroll
    for (int w1 = 0; w1 < 8; ++w1) {
        float p1 = phi1[w1];
        int row = id1[w1];
        #pragma unroll
        for (int w2 = 0; w2 < 8; ++w2) {
            float2 gv = g[row + id2[w2]];
            float wt = p1 * phi2[w2];
            accx += gv.x * wt;
            if (COMPLEX) accy += gv.y * wt;
        }
    }
    if (COMPLEX) ((float2*)out)[m] = make_float2(accx, accy);
    else out[m] = accx;
}

extern "C" void kernel_launch(void* const* d_in, const int* in_sizes, int n_in,
                              void* d_out, int out_size, void* d_ws, size_t ws_size,
                              hipStream_t stream) {
    const float* x  = (const float*)d_in[0];
    const float* fr = (const float*)d_in[1];
    const float* fi = (const float*)d_in[2];
    float2* g = (float2*)d_ws;
    int cplx = (out_size >= 2 * NPTS) ? 1 : 0;
    size_t padded_bytes = (size_t)512 * NCOL * sizeof(float2);  // ~2.03 MiB

    if (ws_size >= padded_bytes) {
        build_ghat<<<1024, 256, 0, stream>>>(fr, fi, g, NCOL);
        fft_lines<<<512, 256, 0, stream>>>(g, NCOL, 1, 8);     // rows + col dup
        fft_lines<<<NCOL, 256, 0, stream>>>(g, 1, NCOL, 0);    // 520 columns
        if (cplx)
            gather_pad<1><<<1024, 256, 0, stream>>>((const float2*)x, g, (float*)d_out);
        else
            gather_pad<0><<<1024, 256, 0, stream>>>((const float2*)x, g, (float*)d_out);
    } else {
        build_ghat<<<1024, 256, 0, stream>>>(fr, fi, g, 512);
        fft_lines<<<512, 256, 0, stream>>>(g, 512, 1, 0);
        fft_lines<<<512, 256, 0, stream>>>(g, 1, 512, 0);
        if (cplx)
            gather_mod<1><<<1024, 256, 0, stream>>>((const float2*)x, g, (float*)d_out);
        else
            gather_mod<0><<<1024, 256, 0, stream>>>((const float2*)x, g, (float*)d_out);
    }
}

// Round 4
// 43.016 us; speedup vs baseline: 2.1386x; 1.2350x over previous
//
#include <hip/hip_runtime.h>
#include <math.h>

#define NPTS 262144
#define B_KB 4.71238898038469f      /* 1.5*pi */
#define B_KB2 22.2066099025f        /* B_KB^2 */
#define PI_F 3.14159265358979f
#define INV_2PI 0.15915494309f      /* 1/(2*pi) */
#define TWO_PI_OVER_N 0.01227184630309f /* 2*pi/512 */
#define NCOL 520                    /* padded row stride: 512 + 8 dup cols */

__device__ __forceinline__ float i0f_dev(float x) {
    float ax = fabsf(x);
    if (ax < 3.75f) {
        float t = ax / 3.75f; t *= t;
        return 1.0f + t*(3.5156229f + t*(3.0899424f + t*(1.2067492f +
               t*(0.2659732f + t*(0.0360768f + t*0.0045813f)))));
    } else {
        float t = 3.75f / ax;
        float p = 0.39894228f + t*(0.01328592f + t*(0.00225319f + t*(-0.00157565f +
                  t*(0.00916281f + t*(-0.02057706f + t*(0.02635537f +
                  t*(-0.01647633f + t*0.00392377f)))))));
        return expf(ax) * p / sqrtf(ax);
    }
}

// Kaiser-Bessel window via raw v_exp/v_rcp: sinh(B*a)/(pi*a), a=sqrt(16-t^2)
__device__ __forceinline__ float phi_win(float t) {
    float s = 16.0f - t * t;
    if (s <= 0.0f) return 0.0f;
    float a = sqrtf(s);
    float ez = __expf(B_KB * a);
    return (ez - __builtin_amdgcn_rcpf(ez)) * INV_2PI * __builtin_amdgcn_rcpf(a);
}

// ---- Fused deconvolution + row FFT (rows with nonzero spectrum only). ----
// Block r in [0,256): grid row i1 = r<128 ? r : r+256 (natural DFT order,
// fftshift pre-applied), frequency k1 = r<128 ? r : r-256. Sign (-1)^(i1+i2)
// folded in so the 2D FFT output needs no ifftshift.
__global__ void rowfft_build(const float* __restrict__ fr,
                             const float* __restrict__ fi,
                             float2* __restrict__ g) {
    __shared__ float2 buf[512];
    int r = blockIdx.x;
    int i1 = (r < 128) ? r : r + 256;
    int k1 = (r < 128) ? r : r - 256;
    int tid = threadIdx.x;                 // 256 threads
    float a1 = TWO_PI_OVER_N * (float)k1;
    float ph1 = i0f_dev(4.0f * sqrtf(B_KB2 - a1 * a1));

    int k2 = tid - 128;                    // [-128, 128)
    int i2 = k2 & 511;
    float a2 = TWO_PI_OVER_N * (float)k2;
    float ph2 = i0f_dev(4.0f * sqrtf(B_KB2 - a2 * a2));
    float inv = 1.0f / (ph1 * ph2);
    if ((i1 + i2) & 1) inv = -inv;
    int fidx = (k1 + 128) * 256 + (k2 + 128);
    float2 v = make_float2(fr[fidx] * inv, fi[fidx] * inv);

    buf[tid] = make_float2(0.0f, 0.0f);
    buf[tid + 256] = make_float2(0.0f, 0.0f);
    __syncthreads();
    int ri = (int)(__brev((unsigned)i2) >> 23);   // 9-bit reversal
    buf[ri] = v;
    __syncthreads();

    #pragma unroll
    for (int s = 1; s <= 9; ++s) {
        int half = 1 << (s - 1);
        int pos = tid & (half - 1);
        int j1 = ((tid >> (s - 1)) << s) | pos;
        float ang = -PI_F * (float)pos / (float)half;
        float sw, cw;
        sincosf(ang, &sw, &cw);
        float2 u = buf[j1];
        float2 w = buf[j1 + half];
        float wr = cw * w.x - sw * w.y;
        float wi = cw * w.y + sw * w.x;
        buf[j1]        = make_float2(u.x + wr, u.y + wi);
        buf[j1 + half] = make_float2(u.x - wr, u.y - wi);
        __syncthreads();
    }
    long base = (long)i1 * NCOL;
    for (int j = tid; j < 512; j += 256) g[base + j] = buf[j];
    if (tid < 8) g[base + 512 + tid] = buf[tid];   // duplicate cols for padding
}

// ---- Column FFT, writes REAL part only into padded real grid. ----
__global__ void colfft_real(const float2* __restrict__ g,
                            float* __restrict__ gre) {
    __shared__ float2 buf[512];
    int c = blockIdx.x;                    // 0..519
    int tid = threadIdx.x;
    for (int j = tid; j < 512; j += 256) {
        int rj = (int)(__brev((unsigned)j) >> 23);
        buf[rj] = g[(long)j * NCOL + c];
    }
    __syncthreads();
    #pragma unroll
    for (int s = 1; s <= 9; ++s) {
        int half = 1 << (s - 1);
        int pos = tid & (half - 1);
        int j1 = ((tid >> (s - 1)) << s) | pos;
        float ang = -PI_F * (float)pos / (float)half;
        float sw, cw;
        sincosf(ang, &sw, &cw);
        float2 u = buf[j1];
        float2 w = buf[j1 + half];
        float wr = cw * w.x - sw * w.y;
        float wi = cw * w.y + sw * w.x;
        buf[j1]        = make_float2(u.x + wr, u.y + wi);
        buf[j1 + half] = make_float2(u.x - wr, u.y - wi);
        __syncthreads();
    }
    for (int j = tid; j < 512; j += 256) gre[(long)j * NCOL + c] = buf[j].x;
}

// ---- Gather from real-only padded grid: 8 rows x 2 float4, all staged. ----
__global__ __launch_bounds__(256, 4)
void gather_real(const float2* __restrict__ x,
                 const float* __restrict__ gre,
                 float* __restrict__ out) {
    int m = blockIdx.x * 256 + threadIdx.x;
    float2 xv = x[m];
    float v1 = xv.x * 512.0f;
    float v2 = xv.y * 512.0f;
    float c1 = ceilf(v1), c2 = ceilf(v2);
    int b1 = (int)c1 - 4, b2 = (int)c2 - 4;
    float f1 = c1 - v1, f2 = c2 - v2;

    float phi1[8], phi2[8];
    int rowb[8];
    #pragma unroll
    for (int w = 0; w < 8; ++w) {
        phi1[w] = phi_win(4.0f - (float)w - f1);
        phi2[w] = phi_win(4.0f - (float)w - f2);
        rowb[w] = ((b1 + w + 768) & 511) * NCOL;
    }
    int cb = (b2 + 768) & 511;

    float4 rA[8], rB[8];
    #pragma unroll
    for (int w = 0; w < 8; ++w) {
        const float4* p = reinterpret_cast<const float4*>(gre + rowb[w] + cb);
        rA[w] = p[0];
        rB[w] = p[1];
    }
    float acc = 0.0f;
    #pragma unroll
    for (int w = 0; w < 8; ++w) {
        acc += phi1[w] * (phi2[0]*rA[w].x + phi2[1]*rA[w].y +
                          phi2[2]*rA[w].z + phi2[3]*rA[w].w +
                          phi2[4]*rB[w].x + phi2[5]*rB[w].y +
                          phi2[6]*rB[w].z + phi2[7]*rB[w].w);
    }
    out[m] = acc;
}

// ================== fallback path (round-3, complex-capable) ==================
__global__ void build_ghat(const float* __restrict__ fr,
                           const float* __restrict__ fi,
                           float2* __restrict__ g, int ldg) {
    int idx = blockIdx.x * 256 + threadIdx.x;
    int i1 = idx >> 9;
    int i2 = idx & 511;
    float2 val = make_float2(0.0f, 0.0f);
    int k1 = 0, k2 = 0;
    bool ok = true;
    if (i1 < 128) k1 = i1; else if (i1 >= 384) k1 = i1 - 512; else ok = false;
    if (ok) { if (i2 < 128) k2 = i2; else if (i2 >= 384) k2 = i2 - 512; else ok = false; }
    if (ok) {
        float a1 = TWO_PI_OVER_N * (float)k1;
        float a2 = TWO_PI_OVER_N * (float)k2;
        float ph1 = i0f_dev(4.0f * sqrtf(B_KB2 - a1*a1));
        float ph2 = i0f_dev(4.0f * sqrtf(B_KB2 - a2*a2));
        float inv = 1.0f / (ph1 * ph2);
        if ((i1 + i2) & 1) inv = -inv;
        int fidx = (k1 + 128) * 256 + (k2 + 128);
        val.x = fr[fidx] * inv;
        val.y = fi[fidx] * inv;
    }
    g[i1 * ldg + i2] = val;
}

__global__ void fft_lines(float2* __restrict__ g, int line_stride,
                          int elem_stride, int ndup) {
    __shared__ float2 buf[512];
    int line = blockIdx.x;
    int tid = threadIdx.x;
    long base = (long)line * line_stride;
    for (int j = tid; j < 512; j += 256) {
        int rj = (int)(__brev((unsigned)j) >> 23);
        buf[rj] = g[base + (long)j * elem_stride];
    }
    __syncthreads();
    #pragma unroll
    for (int s = 1; s <= 9; ++s) {
        int half = 1 << (s - 1);
        int pos = tid & (half - 1);
        int i1 = ((tid >> (s - 1)) << s) | pos;
        float ang = -PI_F * (float)pos / (float)half;
        float sw, cw;
        sincosf(ang, &sw, &cw);
        float2 u = buf[i1];
        float2 v = buf[i1 + half];
        float wr = cw * v.x - sw * v.y;
        float wi = cw * v.y + sw * v.x;
        buf[i1]        = make_float2(u.x + wr, u.y + wi);
        buf[i1 + half] = make_float2(u.x - wr, u.y - wi);
        __syncthreads();
    }
    for (int j = tid; j < 512; j += 256) g[base + (long)j * elem_stride] = buf[j];
    for (int j = tid; j < ndup; j += 256) g[base + 512 + j] = buf[j];
}

template<int COMPLEX>
__global__ __launch_bounds__(256, 4)
void gather_pad(const float2* __restrict__ x,
                const float2* __restrict__ g,
                float* __restrict__ out) {
    int m = blockIdx.x * 256 + threadIdx.x;
    float2 xv = x[m];
    float v1 = xv.x * 512.0f;
    float v2 = xv.y * 512.0f;
    float c1 = ceilf(v1), c2 = ceilf(v2);
    int b1 = (int)c1 - 4, b2 = (int)c2 - 4;
    float f1 = c1 - v1, f2 = c2 - v2;

    float phi1[8], phi2[8];
    int rowb[8];
    #pragma unroll
    for (int w = 0; w < 8; ++w) {
        phi1[w] = phi_win(4.0f - (float)w - f1);
        phi2[w] = phi_win(4.0f - (float)w - f2);
        rowb[w] = ((b1 + w + 768) & 511) * NCOL;
    }
    int cb = (b2 + 768) & 511;

    float accx = 0.0f, accy = 0.0f;
    #pragma unroll
    for (int w1 = 0; w1 < 8; ++w1) {
        const float4* p = reinterpret_cast<const float4*>(g + rowb[w1] + cb);
        float4 va = p[0], vb = p[1], vc = p[2], vd = p[3];
        float p1 = phi1[w1];
        accx += p1 * (phi2[0]*va.x + phi2[1]*va.z + phi2[2]*vb.x + phi2[3]*vb.z +
                      phi2[4]*vc.x + phi2[5]*vc.z + phi2[6]*vd.x + phi2[7]*vd.z);
        if (COMPLEX)
            accy += p1 * (phi2[0]*va.y + phi2[1]*va.w + phi2[2]*vb.y + phi2[3]*vb.w +
                          phi2[4]*vc.y + phi2[5]*vc.w + phi2[6]*vd.y + phi2[7]*vd.w);
    }
    if (COMPLEX) ((float2*)out)[m] = make_float2(accx, accy);
    else out[m] = accx;
}

extern "C" void kernel_launch(void* const* d_in, const int* in_sizes, int n_in,
                              void* d_out, int out_size, void* d_ws, size_t ws_size,
                              hipStream_t stream) {
    const float* x  = (const float*)d_in[0];
    const float* fr = (const float*)d_in[1];
    const float* fi = (const float*)d_in[2];
    int cplx = (out_size >= 2 * NPTS) ? 1 : 0;

    size_t g_bytes   = (size_t)512 * NCOL * sizeof(float2);   // 2,129,920
    size_t gre_bytes = (size_t)512 * NCOL * sizeof(float);    // 1,064,960
    float2* g   = (float2*)d_ws;
    float*  gre = (float*)((char*)d_ws + g_bytes);

    if (!cplx && ws_size >= g_bytes + gre_bytes) {
        // Fast path: fused build+rowFFT, zero middle rows, real-out colFFT.
        hipMemsetAsync((char*)d_ws + (size_t)128 * NCOL * sizeof(float2), 0,
                       (size_t)256 * NCOL * sizeof(float2), stream);
        rowfft_build<<<256, 256, 0, stream>>>(fr, fi, g);
        colfft_real<<<NCOL, 256, 0, stream>>>(g, gre);
        gather_real<<<1024, 256, 0, stream>>>((const float2*)x, gre, (float*)d_out);
    } else if (ws_size >= g_bytes) {
        build_ghat<<<1024, 256, 0, stream>>>(fr, fi, g, NCOL);
        fft_lines<<<512, 256, 0, stream>>>(g, NCOL, 1, 8);
        fft_lines<<<NCOL, 256, 0, stream>>>(g, 1, NCOL, 0);
        if (cplx)
            gather_pad<1><<<1024, 256, 0, stream>>>((const float2*)x, g, (float*)d_out);
        else
            gather_pad<0><<<1024, 256, 0, stream>>>((const float2*)x, g, (float*)d_out);
    } else {
        // Minimal-scratch compact path (512x512 complex, wrap via mod).
        build_ghat<<<1024, 256, 0, stream>>>(fr, fi, g, 512);
        fft_lines<<<512, 256, 0, stream>>>(g, 512, 1, 0);
        fft_lines<<<512, 256, 0, stream>>>(g, 1, 512, 0);
        if (cplx)
            gather_pad<1><<<1024, 256, 0, stream>>>((const float2*)x, g, (float*)d_out);
        else
            gather_pad<0><<<1024, 256, 0, stream>>>((const float2*)x, g, (float*)d_out);
    }
}

// Round 5
// 35.907 us; speedup vs baseline: 2.5620x; 1.1980x over previous
//
#include <hip/hip_runtime.h>
#include <math.h>

#define NPTS 262144
#define B_KB 4.71238898038469f      /* 1.5*pi */
#define B_KB2 22.2066099025f        /* B_KB^2 */
#define PI_F 3.14159265358979f
#define INV_2PI 0.15915494309f      /* 1/(2*pi) */
#define TWO_PI_OVER_N 0.01227184630309f /* 2*pi/512 */
#define NCOL 520                    /* padded row stride: 512 + 8 dup cols */

__device__ __forceinline__ float i0f_dev(float x) {
    float ax = fabsf(x);
    if (ax < 3.75f) {
        float t = ax / 3.75f; t *= t;
        return 1.0f + t*(3.5156229f + t*(3.0899424f + t*(1.2067492f +
               t*(0.2659732f + t*(0.0360768f + t*0.0045813f)))));
    } else {
        float t = 3.75f / ax;
        float p = 0.39894228f + t*(0.01328592f + t*(0.00225319f + t*(-0.00157565f +
                  t*(0.00916281f + t*(-0.02057706f + t*(0.02635537f +
                  t*(-0.01647633f + t*0.00392377f)))))));
        return expf(ax) * p / sqrtf(ax);
    }
}

// Kaiser-Bessel window via raw v_exp/v_rcp: sinh(B*a)/(pi*a), a=sqrt(16-t^2)
__device__ __forceinline__ float phi_win(float t) {
    float s = 16.0f - t * t;
    if (s <= 0.0f) return 0.0f;
    float a = sqrtf(s);
    float ez = __expf(B_KB * a);
    return (ez - __builtin_amdgcn_rcpf(ez)) * INV_2PI * __builtin_amdgcn_rcpf(a);
}

// ---- Fused deconvolution + row FFT (rows with nonzero spectrum only). ----
// Block r in [0,256): grid row i1 = r<128 ? r : r+256 (natural DFT order,
// fftshift pre-applied), frequency k1 = r<128 ? r : r-256. Sign (-1)^(i1+i2)
// folded in so the 2D FFT output needs no ifftshift.
__global__ void rowfft_build(const float* __restrict__ fr,
                             const float* __restrict__ fi,
                             float2* __restrict__ g) {
    __shared__ float2 buf[512];
    int r = blockIdx.x;
    int i1 = (r < 128) ? r : r + 256;
    int k1 = (r < 128) ? r : r - 256;
    int tid = threadIdx.x;                 // 256 threads
    float a1 = TWO_PI_OVER_N * (float)k1;
    float ph1 = i0f_dev(4.0f * sqrtf(B_KB2 - a1 * a1));

    int k2 = tid - 128;                    // [-128, 128)
    int i2 = k2 & 511;
    float a2 = TWO_PI_OVER_N * (float)k2;
    float ph2 = i0f_dev(4.0f * sqrtf(B_KB2 - a2 * a2));
    float inv = 1.0f / (ph1 * ph2);
    if ((i1 + i2) & 1) inv = -inv;
    int fidx = (k1 + 128) * 256 + (k2 + 128);
    float2 v = make_float2(fr[fidx] * inv, fi[fidx] * inv);

    buf[tid] = make_float2(0.0f, 0.0f);
    buf[tid + 256] = make_float2(0.0f, 0.0f);
    __syncthreads();
    int ri = (int)(__brev((unsigned)i2) >> 23);   // 9-bit reversal
    buf[ri] = v;
    __syncthreads();

    #pragma unroll
    for (int s = 1; s <= 9; ++s) {
        int half = 1 << (s - 1);
        int pos = tid & (half - 1);
        int j1 = ((tid >> (s - 1)) << s) | pos;
        float ang = -PI_F * (float)pos / (float)half;
        float sw, cw;
        __sincosf(ang, &sw, &cw);
        float2 u = buf[j1];
        float2 w = buf[j1 + half];
        float wr = cw * w.x - sw * w.y;
        float wi = cw * w.y + sw * w.x;
        buf[j1]        = make_float2(u.x + wr, u.y + wi);
        buf[j1 + half] = make_float2(u.x - wr, u.y - wi);
        __syncthreads();
    }
    long base = (long)i1 * NCOL;
    for (int j = tid; j < 512; j += 256) g[base + j] = buf[j];
    if (tid < 8) g[base + 512 + tid] = buf[tid];   // duplicate cols for padding
}

// ---- Column FFT over the 256 nonzero rows only (middle 256 rows are the
// zero-padding region and are never touched in global memory). Writes REAL
// part only into padded real grid. ----
__global__ void colfft_real(const float2* __restrict__ g,
                            float* __restrict__ gre) {
    __shared__ float2 buf[512];
    int c = blockIdx.x;                    // 0..519
    int tid = threadIdx.x;                 // 256 threads
    buf[tid] = make_float2(0.0f, 0.0f);
    buf[tid + 256] = make_float2(0.0f, 0.0f);
    __syncthreads();
    int r = (tid < 128) ? tid : tid + 256;           // nonzero rows
    int rr = (int)(__brev((unsigned)r) >> 23);       // 9-bit reversal
    buf[rr] = g[(long)r * NCOL + c];
    __syncthreads();
    #pragma unroll
    for (int s = 1; s <= 9; ++s) {
        int half = 1 << (s - 1);
        int pos = tid & (half - 1);
        int j1 = ((tid >> (s - 1)) << s) | pos;
        float ang = -PI_F * (float)pos / (float)half;
        float sw, cw;
        __sincosf(ang, &sw, &cw);
        float2 u = buf[j1];
        float2 w = buf[j1 + half];
        float wr = cw * w.x - sw * w.y;
        float wi = cw * w.y + sw * w.x;
        buf[j1]        = make_float2(u.x + wr, u.y + wi);
        buf[j1 + half] = make_float2(u.x - wr, u.y - wi);
        __syncthreads();
    }
    for (int j = tid; j < 512; j += 256) gre[(long)j * NCOL + c] = buf[j].x;
}

// ---- Gather from real-only padded grid: 8 rows x 2 float4, all staged. ----
__global__ __launch_bounds__(256, 4)
void gather_real(const float2* __restrict__ x,
                 const float* __restrict__ gre,
                 float* __restrict__ out) {
    int m = blockIdx.x * 256 + threadIdx.x;
    float2 xv = x[m];
    float v1 = xv.x * 512.0f;
    float v2 = xv.y * 512.0f;
    float c1 = ceilf(v1), c2 = ceilf(v2);
    int b1 = (int)c1 - 4, b2 = (int)c2 - 4;
    float f1 = c1 - v1, f2 = c2 - v2;

    float phi1[8], phi2[8];
    int rowb[8];
    #pragma unroll
    for (int w = 0; w < 8; ++w) {
        phi1[w] = phi_win(4.0f - (float)w - f1);
        phi2[w] = phi_win(4.0f - (float)w - f2);
        rowb[w] = ((b1 + w + 768) & 511) * NCOL;
    }
    int cb = (b2 + 768) & 511;

    float4 rA[8], rB[8];
    #pragma unroll
    for (int w = 0; w < 8; ++w) {
        const float4* p = reinterpret_cast<const float4*>(gre + rowb[w] + cb);
        rA[w] = p[0];
        rB[w] = p[1];
    }
    float acc = 0.0f;
    #pragma unroll
    for (int w = 0; w < 8; ++w) {
        acc += phi1[w] * (phi2[0]*rA[w].x + phi2[1]*rA[w].y +
                          phi2[2]*rA[w].z + phi2[3]*rA[w].w +
                          phi2[4]*rB[w].x + phi2[5]*rB[w].y +
                          phi2[6]*rB[w].z + phi2[7]*rB[w].w);
    }
    out[m] = acc;
}

// ================== fallback path (complex-capable) ==================
__global__ void build_ghat(const float* __restrict__ fr,
                           const float* __restrict__ fi,
                           float2* __restrict__ g, int ldg) {
    int idx = blockIdx.x * 256 + threadIdx.x;
    int i1 = idx >> 9;
    int i2 = idx & 511;
    float2 val = make_float2(0.0f, 0.0f);
    int k1 = 0, k2 = 0;
    bool ok = true;
    if (i1 < 128) k1 = i1; else if (i1 >= 384) k1 = i1 - 512; else ok = false;
    if (ok) { if (i2 < 128) k2 = i2; else if (i2 >= 384) k2 = i2 - 512; else ok = false; }
    if (ok) {
        float a1 = TWO_PI_OVER_N * (float)k1;
        float a2 = TWO_PI_OVER_N * (float)k2;
        float ph1 = i0f_dev(4.0f * sqrtf(B_KB2 - a1*a1));
        float ph2 = i0f_dev(4.0f * sqrtf(B_KB2 - a2*a2));
        float inv = 1.0f / (ph1 * ph2);
        if ((i1 + i2) & 1) inv = -inv;
        int fidx = (k1 + 128) * 256 + (k2 + 128);
        val.x = fr[fidx] * inv;
        val.y = fi[fidx] * inv;
    }
    g[i1 * ldg + i2] = val;
}

__global__ void fft_lines(float2* __restrict__ g, int line_stride,
                          int elem_stride, int ndup) {
    __shared__ float2 buf[512];
    int line = blockIdx.x;
    int tid = threadIdx.x;
    long base = (long)line * line_stride;
    for (int j = tid; j < 512; j += 256) {
        int rj = (int)(__brev((unsigned)j) >> 23);
        buf[rj] = g[base + (long)j * elem_stride];
    }
    __syncthreads();
    #pragma unroll
    for (int s = 1; s <= 9; ++s) {
        int half = 1 << (s - 1);
        int pos = tid & (half - 1);
        int i1 = ((tid >> (s - 1)) << s) | pos;
        float ang = -PI_F * (float)pos / (float)half;
        float sw, cw;
        __sincosf(ang, &sw, &cw);
        float2 u = buf[i1];
        float2 v = buf[i1 + half];
        float wr = cw * v.x - sw * v.y;
        float wi = cw * v.y + sw * v.x;
        buf[i1]        = make_float2(u.x + wr, u.y + wi);
        buf[i1 + half] = make_float2(u.x - wr, u.y - wi);
        __syncthreads();
    }
    for (int j = tid; j < 512; j += 256) g[base + (long)j * elem_stride] = buf[j];
    for (int j = tid; j < ndup; j += 256) g[base + 512 + j] = buf[j];
}

template<int COMPLEX>
__global__ __launch_bounds__(256, 4)
void gather_pad(const float2* __restrict__ x,
                const float2* __restrict__ g,
                float* __restrict__ out) {
    int m = blockIdx.x * 256 + threadIdx.x;
    float2 xv = x[m];
    float v1 = xv.x * 512.0f;
    float v2 = xv.y * 512.0f;
    float c1 = ceilf(v1), c2 = ceilf(v2);
    int b1 = (int)c1 - 4, b2 = (int)c2 - 4;
    float f1 = c1 - v1, f2 = c2 - v2;

    float phi1[8], phi2[8];
    int rowb[8];
    #pragma unroll
    for (int w = 0; w < 8; ++w) {
        phi1[w] = phi_win(4.0f - (float)w - f1);
        phi2[w] = phi_win(4.0f - (float)w - f2);
        rowb[w] = ((b1 + w + 768) & 511) * NCOL;
    }
    int cb = (b2 + 768) & 511;

    float accx = 0.0f, accy = 0.0f;
    #pragma unroll
    for (int w1 = 0; w1 < 8; ++w1) {
        const float4* p = reinterpret_cast<const float4*>(g + rowb[w1] + cb);
        float4 va = p[0], vb = p[1], vc = p[2], vd = p[3];
        float p1 = phi1[w1];
        accx += p1 * (phi2[0]*va.x + phi2[1]*va.z + phi2[2]*vb.x + phi2[3]*vb.z +
                      phi2[4]*vc.x + phi2[5]*vc.z + phi2[6]*vd.x + phi2[7]*vd.z);
        if (COMPLEX)
            accy += p1 * (phi2[0]*va.y + phi2[1]*va.w + phi2[2]*vb.y + phi2[3]*vb.w +
                          phi2[4]*vc.y + phi2[5]*vc.w + phi2[6]*vd.y + phi2[7]*vd.w);
    }
    if (COMPLEX) ((float2*)out)[m] = make_float2(accx, accy);
    else out[m] = accx;
}

extern "C" void kernel_launch(void* const* d_in, const int* in_sizes, int n_in,
                              void* d_out, int out_size, void* d_ws, size_t ws_size,
                              hipStream_t stream) {
    const float* x  = (const float*)d_in[0];
    const float* fr = (const float*)d_in[1];
    const float* fi = (const float*)d_in[2];
    int cplx = (out_size >= 2 * NPTS) ? 1 : 0;

    size_t g_bytes   = (size_t)512 * NCOL * sizeof(float2);   // 2,129,920
    size_t gre_bytes = (size_t)512 * NCOL * sizeof(float);    // 1,064,960
    float2* g   = (float2*)d_ws;
    float*  gre = (float*)((char*)d_ws + g_bytes);

    if (!cplx && ws_size >= g_bytes + gre_bytes) {
        // Fast path: fused build+rowFFT, zero-row-aware colFFT (no memset),
        // real-only padded grid, staged float4 gather.
        rowfft_build<<<256, 256, 0, stream>>>(fr, fi, g);
        colfft_real<<<NCOL, 256, 0, stream>>>(g, gre);
        gather_real<<<1024, 256, 0, stream>>>((const float2*)x, gre, (float*)d_out);
    } else if (ws_size >= g_bytes) {
        build_ghat<<<1024, 256, 0, stream>>>(fr, fi, g, NCOL);
        fft_lines<<<512, 256, 0, stream>>>(g, NCOL, 1, 8);
        fft_lines<<<NCOL, 256, 0, stream>>>(g, 1, NCOL, 0);
        if (cplx)
            gather_pad<1><<<1024, 256, 0, stream>>>((const float2*)x, g, (float*)d_out);
        else
            gather_pad<0><<<1024, 256, 0, stream>>>((const float2*)x, g, (float*)d_out);
    } else {
        build_ghat<<<1024, 256, 0, stream>>>(fr, fi, g, 512);
        fft_lines<<<512, 256, 0, stream>>>(g, 512, 1, 0);
        fft_lines<<<512, 256, 0, stream>>>(g, 1, 512, 0);
        if (cplx)
            gather_pad<1><<<1024, 256, 0, stream>>>((const float2*)x, g, (float*)d_out);
        else
            gather_pad<0><<<1024, 256, 0, stream>>>((const float2*)x, g, (float*)d_out);
    }
}

// Round 6
// 35.711 us; speedup vs baseline: 2.5761x; 1.0055x over previous
//
#include <hip/hip_runtime.h>
#include <math.h>

#define NPTS 262144
#define B_KB 4.71238898038469f      /* 1.5*pi */
#define B_KB2 22.2066099025f        /* B_KB^2 */
#define PI_F 3.14159265358979f
#define INV_2PI 0.15915494309f      /* 1/(2*pi) */
#define TWO_PI_OVER_N 0.01227184630309f /* 2*pi/512 */
#define NCOL 520                    /* padded complex row stride */
#define NCOLH 528                   /* padded f16 row stride (16B-aligned rows) */
#define PLANE (512 * NCOLH)         /* one parity plane, elements */
#define S_SCALE 1.37438953472e11f   /* 2^37: grid rescale into f16 range */
#define INV_S   7.27595761418e-12f  /* 2^-37 */

typedef _Float16 half8v __attribute__((ext_vector_type(8)));

__device__ __forceinline__ float i0f_dev(float x) {
    float ax = fabsf(x);
    if (ax < 3.75f) {
        float t = ax / 3.75f; t *= t;
        return 1.0f + t*(3.5156229f + t*(3.0899424f + t*(1.2067492f +
               t*(0.2659732f + t*(0.0360768f + t*0.0045813f)))));
    } else {
        float t = 3.75f / ax;
        float p = 0.39894228f + t*(0.01328592f + t*(0.00225319f + t*(-0.00157565f +
                  t*(0.00916281f + t*(-0.02057706f + t*(0.02635537f +
                  t*(-0.01647633f + t*0.00392377f)))))));
        return expf(ax) * p / sqrtf(ax);
    }
}

// Kaiser-Bessel window via raw v_exp/v_rcp: sinh(B*a)/(pi*a), a=sqrt(16-t^2)
__device__ __forceinline__ float phi_win(float t) {
    float s = 16.0f - t * t;
    if (s <= 0.0f) return 0.0f;
    float a = sqrtf(s);
    float ez = __expf(B_KB * a);
    return (ez - __builtin_amdgcn_rcpf(ez)) * INV_2PI * __builtin_amdgcn_rcpf(a);
}

// ---- Fused deconvolution + row FFT (rows with nonzero spectrum only). ----
// Scale S folded in so the f16 grid lands in normal range.
__global__ void rowfft_build(const float* __restrict__ fr,
                             const float* __restrict__ fi,
                             float2* __restrict__ g) {
    __shared__ float2 buf[512];
    int r = blockIdx.x;
    int i1 = (r < 128) ? r : r + 256;
    int k1 = (r < 128) ? r : r - 256;
    int tid = threadIdx.x;                 // 256 threads
    float a1 = TWO_PI_OVER_N * (float)k1;
    float ph1 = i0f_dev(4.0f * sqrtf(B_KB2 - a1 * a1));

    int k2 = tid - 128;                    // [-128, 128)
    int i2 = k2 & 511;
    float a2 = TWO_PI_OVER_N * (float)k2;
    float ph2 = i0f_dev(4.0f * sqrtf(B_KB2 - a2 * a2));
    float inv = S_SCALE / (ph1 * ph2);
    if ((i1 + i2) & 1) inv = -inv;
    int fidx = (k1 + 128) * 256 + (k2 + 128);
    float2 v = make_float2(fr[fidx] * inv, fi[fidx] * inv);

    buf[tid] = make_float2(0.0f, 0.0f);
    buf[tid + 256] = make_float2(0.0f, 0.0f);
    __syncthreads();
    int ri = (int)(__brev((unsigned)i2) >> 23);   // 9-bit reversal
    buf[ri] = v;
    __syncthreads();

    #pragma unroll
    for (int s = 1; s <= 9; ++s) {
        int half = 1 << (s - 1);
        int pos = tid & (half - 1);
        int j1 = ((tid >> (s - 1)) << s) | pos;
        float ang = -PI_F * (float)pos / (float)half;
        float sw, cw;
        __sincosf(ang, &sw, &cw);
        float2 u = buf[j1];
        float2 w = buf[j1 + half];
        float wr = cw * w.x - sw * w.y;
        float wi = cw * w.y + sw * w.x;
        buf[j1]        = make_float2(u.x + wr, u.y + wi);
        buf[j1 + half] = make_float2(u.x - wr, u.y - wi);
        __syncthreads();
    }
    long base = (long)i1 * NCOL;
    for (int j = tid; j < 512; j += 256) g[base + j] = buf[j];
    if (tid < 8) g[base + 512 + tid] = buf[tid];   // duplicate cols for padding
}

// ---- Column FFT over the 256 nonzero rows; REAL part only, stored as f16
// into 4 shifted parity planes (plane d holds grid col c at index c-d) so the
// gather's 16B row-loads are always >=8B aligned. ----
__global__ void colfft_f16(const float2* __restrict__ g,
                           _Float16* __restrict__ gh) {
    __shared__ float2 buf[512];
    int c = blockIdx.x;                    // 0..519
    int tid = threadIdx.x;                 // 256 threads
    buf[tid] = make_float2(0.0f, 0.0f);
    buf[tid + 256] = make_float2(0.0f, 0.0f);
    __syncthreads();
    int r = (tid < 128) ? tid : tid + 256;           // nonzero rows
    int rr = (int)(__brev((unsigned)r) >> 23);       // 9-bit reversal
    buf[rr] = g[(long)r * NCOL + c];
    __syncthreads();
    #pragma unroll
    for (int s = 1; s <= 9; ++s) {
        int half = 1 << (s - 1);
        int pos = tid & (half - 1);
        int j1 = ((tid >> (s - 1)) << s) | pos;
        float ang = -PI_F * (float)pos / (float)half;
        float sw, cw;
        __sincosf(ang, &sw, &cw);
        float2 u = buf[j1];
        float2 w = buf[j1 + half];
        float wr = cw * w.x - sw * w.y;
        float wi = cw * w.y + sw * w.x;
        buf[j1]        = make_float2(u.x + wr, u.y + wi);
        buf[j1 + half] = make_float2(u.x - wr, u.y - wi);
        __syncthreads();
    }
    for (int j = tid; j < 512; j += 256) {
        _Float16 h = (_Float16)buf[j].x;
        int rb = j * NCOLH + c;
        gh[rb] = h;                                   // plane 0
        if (c >= 1) gh[PLANE     + rb - 1] = h;       // plane 1
        if (c >= 2) gh[2 * PLANE + rb - 2] = h;       // plane 2
        if (c >= 3) gh[3 * PLANE + rb - 3] = h;       // plane 3
    }
}

// ---- Gather from f16 parity planes: 8 rows x one dwordx4 (8 halves). ----
__global__ __launch_bounds__(256, 4)
void gather_f16(const float2* __restrict__ x,
                const _Float16* __restrict__ gh,
                float* __restrict__ out) {
    int m = blockIdx.x * 256 + threadIdx.x;
    float2 xv = x[m];
    float v1 = xv.x * 512.0f;
    float v2 = xv.y * 512.0f;
    float c1 = ceilf(v1), c2 = ceilf(v2);
    int b1 = (int)c1 - 4, b2 = (int)c2 - 4;
    float f1 = c1 - v1, f2 = c2 - v2;

    float phi1[8], phi2[8];
    int rowb[8];
    #pragma unroll
    for (int w = 0; w < 8; ++w) {
        phi1[w] = phi_win(4.0f - (float)w - f1) * INV_S;
        phi2[w] = phi_win(4.0f - (float)w - f2);
        rowb[w] = ((b1 + w + 768) & 511) * NCOLH;
    }
    int cb = (b2 + 768) & 511;
    int d  = cb & 3;
    const _Float16* base = gh + d * PLANE + (cb - d);

    half8v rv[8];
    #pragma unroll
    for (int w = 0; w < 8; ++w) {
        rv[w] = *reinterpret_cast<const half8v*>(base + rowb[w]);
    }
    float acc = 0.0f;
    #pragma unroll
    for (int w = 0; w < 8; ++w) {
        float rs = phi2[0]*(float)rv[w][0] + phi2[1]*(float)rv[w][1] +
                   phi2[2]*(float)rv[w][2] + phi2[3]*(float)rv[w][3] +
                   phi2[4]*(float)rv[w][4] + phi2[5]*(float)rv[w][5] +
                   phi2[6]*(float)rv[w][6] + phi2[7]*(float)rv[w][7];
        acc += phi1[w] * rs;
    }
    out[m] = acc;
}

// ================== fallback path (complex-capable, f32) ==================
__global__ void build_ghat(const float* __restrict__ fr,
                           const float* __restrict__ fi,
                           float2* __restrict__ g, int ldg) {
    int idx = blockIdx.x * 256 + threadIdx.x;
    int i1 = idx >> 9;
    int i2 = idx & 511;
    float2 val = make_float2(0.0f, 0.0f);
    int k1 = 0, k2 = 0;
    bool ok = true;
    if (i1 < 128) k1 = i1; else if (i1 >= 384) k1 = i1 - 512; else ok = false;
    if (ok) { if (i2 < 128) k2 = i2; else if (i2 >= 384) k2 = i2 - 512; else ok = false; }
    if (ok) {
        float a1 = TWO_PI_OVER_N * (float)k1;
        float a2 = TWO_PI_OVER_N * (float)k2;
        float ph1 = i0f_dev(4.0f * sqrtf(B_KB2 - a1*a1));
        float ph2 = i0f_dev(4.0f * sqrtf(B_KB2 - a2*a2));
        float inv = 1.0f / (ph1 * ph2);
        if ((i1 + i2) & 1) inv = -inv;
        int fidx = (k1 + 128) * 256 + (k2 + 128);
        val.x = fr[fidx] * inv;
        val.y = fi[fidx] * inv;
    }
    g[i1 * ldg + i2] = val;
}

__global__ void fft_lines(float2* __restrict__ g, int line_stride,
                          int elem_stride, int ndup) {
    __shared__ float2 buf[512];
    int line = blockIdx.x;
    int tid = threadIdx.x;
    long base = (long)line * line_stride;
    for (int j = tid; j < 512; j += 256) {
        int rj = (int)(__brev((unsigned)j) >> 23);
        buf[rj] = g[base + (long)j * elem_stride];
    }
    __syncthreads();
    #pragma unroll
    for (int s = 1; s <= 9; ++s) {
        int half = 1 << (s - 1);
        int pos = tid & (half - 1);
        int i1 = ((tid >> (s - 1)) << s) | pos;
        float ang = -PI_F * (float)pos / (float)half;
        float sw, cw;
        __sincosf(ang, &sw, &cw);
        float2 u = buf[i1];
        float2 v = buf[i1 + half];
        float wr = cw * v.x - sw * v.y;
        float wi = cw * v.y + sw * v.x;
        buf[i1]        = make_float2(u.x + wr, u.y + wi);
        buf[i1 + half] = make_float2(u.x - wr, u.y - wi);
        __syncthreads();
    }
    for (int j = tid; j < 512; j += 256) g[base + (long)j * elem_stride] = buf[j];
    for (int j = tid; j < ndup; j += 256) g[base + 512 + j] = buf[j];
}

template<int COMPLEX>
__global__ __launch_bounds__(256, 4)
void gather_pad(const float2* __restrict__ x,
                const float2* __restrict__ g,
                float* __restrict__ out) {
    int m = blockIdx.x * 256 + threadIdx.x;
    float2 xv = x[m];
    float v1 = xv.x * 512.0f;
    float v2 = xv.y * 512.0f;
    float c1 = ceilf(v1), c2 = ceilf(v2);
    int b1 = (int)c1 - 4, b2 = (int)c2 - 4;
    float f1 = c1 - v1, f2 = c2 - v2;

    float phi1[8], phi2[8];
    int rowb[8];
    #pragma unroll
    for (int w = 0; w < 8; ++w) {
        phi1[w] = phi_win(4.0f - (float)w - f1);
        phi2[w] = phi_win(4.0f - (float)w - f2);
        rowb[w] = ((b1 + w + 768) & 511) * NCOL;
    }
    int cb = (b2 + 768) & 511;

    float accx = 0.0f, accy = 0.0f;
    #pragma unroll
    for (int w1 = 0; w1 < 8; ++w1) {
        const float4* p = reinterpret_cast<const float4*>(g + rowb[w1] + cb);
        float4 va = p[0], vb = p[1], vc = p[2], vd = p[3];
        float p1 = phi1[w1];
        accx += p1 * (phi2[0]*va.x + phi2[1]*va.z + phi2[2]*vb.x + phi2[3]*vb.z +
                      phi2[4]*vc.x + phi2[5]*vc.z + phi2[6]*vd.x + phi2[7]*vd.z);
        if (COMPLEX)
            accy += p1 * (phi2[0]*va.y + phi2[1]*va.w + phi2[2]*vb.y + phi2[3]*vb.w +
                          phi2[4]*vc.y + phi2[5]*vc.w + phi2[6]*vd.y + phi2[7]*vd.w);
    }
    if (COMPLEX) ((float2*)out)[m] = make_float2(accx, accy);
    else out[m] = accx;
}

extern "C" void kernel_launch(void* const* d_in, const int* in_sizes, int n_in,
                              void* d_out, int out_size, void* d_ws, size_t ws_size,
                              hipStream_t stream) {
    const float* x  = (const float*)d_in[0];
    const float* fr = (const float*)d_in[1];
    const float* fi = (const float*)d_in[2];
    int cplx = (out_size >= 2 * NPTS) ? 1 : 0;

    size_t g_bytes  = (size_t)512 * NCOL * sizeof(float2);    // 2,129,920
    size_t gh_bytes = (size_t)4 * PLANE * sizeof(_Float16);   // 2,162,688
    float2*   g  = (float2*)d_ws;
    _Float16* gh = (_Float16*)((char*)d_ws + g_bytes);

    if (!cplx && ws_size >= g_bytes + gh_bytes) {
        // Fast path: fused build+rowFFT, zero-row-aware colFFT -> f16 parity
        // planes, 8-load gather.
        rowfft_build<<<256, 256, 0, stream>>>(fr, fi, g);
        colfft_f16<<<NCOL, 256, 0, stream>>>(g, gh);
        gather_f16<<<1024, 256, 0, stream>>>((const float2*)x, gh, (float*)d_out);
    } else if (ws_size >= g_bytes) {
        build_ghat<<<1024, 256, 0, stream>>>(fr, fi, g, NCOL);
        fft_lines<<<512, 256, 0, stream>>>(g, NCOL, 1, 8);
        fft_lines<<<NCOL, 256, 0, stream>>>(g, 1, NCOL, 0);
        if (cplx)
            gather_pad<1><<<1024, 256, 0, stream>>>((const float2*)x, g, (float*)d_out);
        else
            gather_pad<0><<<1024, 256, 0, stream>>>((const float2*)x, g, (float*)d_out);
    } else {
        build_ghat<<<1024, 256, 0, stream>>>(fr, fi, g, 512);
        fft_lines<<<512, 256, 0, stream>>>(g, 512, 1, 0);
        fft_lines<<<512, 256, 0, stream>>>(g, 1, 512, 0);
        if (cplx)
            gather_pad<1><<<1024, 256, 0, stream>>>((const float2*)x, g, (float*)d_out);
        else
            gather_pad<0><<<1024, 256, 0, stream>>>((const float2*)x, g, (float*)d_out);
    }
}